// Round 4
// baseline (91032.715 us; speedup 1.0000x reference)
//
#include <hip/hip_runtime.h>
#include <cstddef>
#include <cstdint>

// SentimentAnalysis: BiLSTM(H=512) -> LSTM(1024) -> attn pool -> fc -> lin
// B=64, T=512, E=300, H=512, C=2. All fp32.
//
// ws evidence: round2 (no guard, 770MB) -> page-fault abort; round3 (guard,
// 289MB) -> stub-identical zero output => guard tripped => ws_size < 289MiB.
// This version needs ~86 MiB:
//   hb [B,T,512] (64 MiB)   - full bwd hidden states (irreducible)
//   hf_chunk [B,32,512] (4) - fwd h, one chunk at a time (layer2 interleaved)
//   chunk region (16 MiB)   - buf_b / buf_f [B,32,2048] and buf_s [B,16,4096]
//                             (aliased; lifetimes disjoint in stream order)
//   hs eliminated: scores fused into lstm2_step (wave-reduce + atomicAdd),
//   ctx accumulated online (no max-sub; |s|<=16 so e^s is safe in fp32),
//   rolling 2-slot hroll for h_prev.
// Guard: if ws_size still too small, write sentinel 1e6 to out[0].

#define T_SEQ 512
#define NB 64
#define TC1 32   // layer-1 chunk (x-projections, lstm1 steps)
#define TC2 16   // layer-2 sub-chunk (buf_s, lstm2 steps)

__device__ __forceinline__ float sigf(float x) {
    return 1.0f / (1.0f + expf(-x));
}

// ---------------- Tiled SGEMM: C[M,N] = (A@B) [+ C] [+ bias], opt relu -----
// BM=BN=128, BK=8, 256 threads, 8x8 per thread.
// Row remap (chunked): local row r -> global A-row (r>>tsh)*Trows + t0 + (r&tcm).
// accum: C += A@B (no bias). else: C = A@B + bias.
__global__ __launch_bounds__(256) void sgemm_bias(
    const float* __restrict__ A, const float* __restrict__ B,
    const float* __restrict__ bias, float* __restrict__ C,
    int M, int N, int K, int act, int accum,
    int chunked, int t0, int tsh, int tcm, int Trows)
{
    __shared__ float As[8][128];
    __shared__ float Bs[8][128];
    int tid = threadIdx.x;
    int row0 = blockIdx.y * 128, col0 = blockIdx.x * 128;
    int arow = tid >> 1, ak0 = (tid & 1) * 4;       // A: 2 thr/row, 4 k each
    int bk = tid >> 5, bcol = (tid & 31) * 4;       // B: float4 along N
    int ty = tid >> 4, tx = tid & 15;               // 16x16 thread grid
    float acc[8][8] = {};
    int r = row0 + arow;
    int grow = chunked ? ((r >> tsh) * Trows + t0 + (r & tcm)) : r;
    const float* Aptr = A + (size_t)grow * K;
    bool arow_ok = r < M;

    for (int k0 = 0; k0 < K; k0 += 8) {
#pragma unroll
        for (int i = 0; i < 4; i++) {
            int k = k0 + ak0 + i;
            As[ak0 + i][arow] = (arow_ok && k < K) ? Aptr[k] : 0.0f;
        }
        {
            int k = k0 + bk;
            float4 v = make_float4(0.f, 0.f, 0.f, 0.f);
            if (k < K) v = *(const float4*)&B[(size_t)k * N + col0 + bcol];
            *(float4*)&Bs[bk][bcol] = v;
        }
        __syncthreads();
#pragma unroll
        for (int kk = 0; kk < 8; kk++) {
            float a[8], b[8];
#pragma unroll
            for (int i = 0; i < 8; i++) a[i] = As[kk][ty * 8 + i];
#pragma unroll
            for (int j = 0; j < 8; j++) b[j] = Bs[kk][tx * 8 + j];
#pragma unroll
            for (int i = 0; i < 8; i++)
#pragma unroll
                for (int j = 0; j < 8; j++)
                    acc[i][j] = fmaf(a[i], b[j], acc[i][j]);
        }
        __syncthreads();
    }

    float bj[8];
#pragma unroll
    for (int j = 0; j < 8; j++) bj[j] = accum ? 0.0f : bias[col0 + tx * 8 + j];
#pragma unroll
    for (int i = 0; i < 8; i++) {
        int rr = row0 + ty * 8 + i;
        if (rr >= M) continue;
        float* crow = &C[(size_t)rr * N + col0 + tx * 8];
#pragma unroll
        for (int j = 0; j < 8; j += 4) {
            float4 v;
            v.x = acc[i][j + 0] + bj[j + 0];
            v.y = acc[i][j + 1] + bj[j + 1];
            v.z = acc[i][j + 2] + bj[j + 2];
            v.w = acc[i][j + 3] + bj[j + 3];
            if (accum) {
                float4 o = *(const float4*)&crow[j];
                v.x += o.x; v.y += o.y; v.z += o.z; v.w += o.w;
            }
            if (act) {
                v.x = fmaxf(v.x, 0.f); v.y = fmaxf(v.y, 0.f);
                v.z = fmaxf(v.z, 0.f); v.w = fmaxf(v.w, 0.f);
            }
            *(float4*)&crow[j] = v;
        }
    }
}

// ---------------- LSTM1 forward step ---------------------------------------
// 64 blocks: ut(8, 64 u) x bt(8, 8 b). Thread: lane=u, wave=b-slot, 2 b rows.
// buf_f [B][TC1][2048]; writes hf_chunk [B][TC1][512] and hf_roll[t&1][B][512].
__global__ __launch_bounds__(256) void lstm1f_step(
    const float* __restrict__ buf_f, const float* __restrict__ Wh_f,
    float* __restrict__ hf_chunk, float* __restrict__ hf_roll,
    float* __restrict__ c_f, int t)
{
    int ut = blockIdx.x & 7, bt = blockIdx.x >> 3;
    int tid = threadIdx.x;
    int lane = tid & 63, w = tid >> 6;
    int u = ut * 64 + lane;
    int bb[2] = { bt * 8 + w, bt * 8 + w + 4 };
    int tl = t & (TC1 - 1);

    float acc[2][4];
#pragma unroll
    for (int j = 0; j < 2; j++) {
        size_t g = ((size_t)bb[j] * TC1 + tl) * 2048;
        acc[j][0] = buf_f[g + u];
        acc[j][1] = buf_f[g + 512 + u];
        acc[j][2] = buf_f[g + 1024 + u];
        acc[j][3] = buf_f[g + 1536 + u];
    }

    if (t > 0) {
        const float* hp = hf_roll + ((t - 1) & 1) * (NB * 512);
        const float* h0 = hp + bb[0] * 512;
        const float* h1 = hp + bb[1] * 512;
#pragma unroll 4
        for (int k = 0; k < 512; k++) {
            float hk0 = h0[k], hk1 = h1[k];
            const float* wr = Wh_f + ((size_t)k << 11);
            float wi = wr[u], wf = wr[u + 512], wg = wr[u + 1024], wo = wr[u + 1536];
            acc[0][0] = fmaf(hk0, wi, acc[0][0]);
            acc[0][1] = fmaf(hk0, wf, acc[0][1]);
            acc[0][2] = fmaf(hk0, wg, acc[0][2]);
            acc[0][3] = fmaf(hk0, wo, acc[0][3]);
            acc[1][0] = fmaf(hk1, wi, acc[1][0]);
            acc[1][1] = fmaf(hk1, wf, acc[1][1]);
            acc[1][2] = fmaf(hk1, wg, acc[1][2]);
            acc[1][3] = fmaf(hk1, wo, acc[1][3]);
        }
    }

    float* hc = hf_roll + (t & 1) * (NB * 512);
#pragma unroll
    for (int j = 0; j < 2; j++) {
        int b = bb[j];
        float iv = sigf(acc[j][0]);
        float fv = sigf(acc[j][1]);
        float gv = tanhf(acc[j][2]);
        float ov = sigf(acc[j][3]);
        float cprev = (t > 0) ? c_f[b * 512 + u] : 0.0f;
        float c = fv * cprev + iv * gv;
        float h = ov * tanhf(c);
        c_f[b * 512 + u] = c;
        hc[b * 512 + u] = h;
        hf_chunk[((size_t)b * TC1 + tl) * 512 + u] = h;
    }
}

// ---------------- LSTM1 backward step --------------------------------------
// hb [B][T][512] full; h_prev = hb[b][t_eff+1]. buf_b tl = TC1-1-(t&31).
__global__ __launch_bounds__(256) void lstm1b_step(
    const float* __restrict__ buf_b, const float* __restrict__ Wh_b,
    float* __restrict__ hb, float* __restrict__ c_b, int t)
{
    int ut = blockIdx.x & 7, bt = blockIdx.x >> 3;
    int tid = threadIdx.x;
    int lane = tid & 63, w = tid >> 6;
    int u = ut * 64 + lane;
    int bb[2] = { bt * 8 + w, bt * 8 + w + 4 };
    int t_eff = T_SEQ - 1 - t;
    int tl = (TC1 - 1) - (t & (TC1 - 1));

    float acc[2][4];
#pragma unroll
    for (int j = 0; j < 2; j++) {
        size_t g = ((size_t)bb[j] * TC1 + tl) * 2048;
        acc[j][0] = buf_b[g + u];
        acc[j][1] = buf_b[g + 512 + u];
        acc[j][2] = buf_b[g + 1024 + u];
        acc[j][3] = buf_b[g + 1536 + u];
    }

    if (t > 0) {
        const float* h0 = hb + ((size_t)bb[0] * T_SEQ + t_eff + 1) * 512;
        const float* h1 = hb + ((size_t)bb[1] * T_SEQ + t_eff + 1) * 512;
#pragma unroll 4
        for (int k = 0; k < 512; k++) {
            float hk0 = h0[k], hk1 = h1[k];
            const float* wr = Wh_b + ((size_t)k << 11);
            float wi = wr[u], wf = wr[u + 512], wg = wr[u + 1024], wo = wr[u + 1536];
            acc[0][0] = fmaf(hk0, wi, acc[0][0]);
            acc[0][1] = fmaf(hk0, wf, acc[0][1]);
            acc[0][2] = fmaf(hk0, wg, acc[0][2]);
            acc[0][3] = fmaf(hk0, wo, acc[0][3]);
            acc[1][0] = fmaf(hk1, wi, acc[1][0]);
            acc[1][1] = fmaf(hk1, wf, acc[1][1]);
            acc[1][2] = fmaf(hk1, wg, acc[1][2]);
            acc[1][3] = fmaf(hk1, wo, acc[1][3]);
        }
    }

#pragma unroll
    for (int j = 0; j < 2; j++) {
        int b = bb[j];
        float iv = sigf(acc[j][0]);
        float fv = sigf(acc[j][1]);
        float gv = tanhf(acc[j][2]);
        float ov = sigf(acc[j][3]);
        float cprev = (t > 0) ? c_b[b * 512 + u] : 0.0f;
        float c = fv * cprev + iv * gv;
        float h = ov * tanhf(c);
        c_b[b * 512 + u] = c;
        hb[((size_t)b * T_SEQ + t_eff) * 512 + u] = h;
    }
}

// ---------------- LSTM2 step (hidden 1024) + fused score & ctx accumulation
// 128 blocks: ut(16) x bt(8). buf_s [B][TC2][4096], tl = t&15.
// h_prev from hroll[(t-1)&1]; writes hroll[t&1].
// Fused: scores[b*T+t] += wave-reduced tanh(h).attn_w (atomicAdd);
//        ctx_num[b*1024+u] += exp(scores[b*T+t-1]) * hroll_prev[b][u].
__global__ __launch_bounds__(256) void lstm2_step(
    const float* __restrict__ buf_s, const float* __restrict__ Wh_s,
    float* __restrict__ hroll, float* __restrict__ c_s,
    float* __restrict__ scores, float* __restrict__ ctx_num,
    const float* __restrict__ attn_w, int t)
{
    int ut = blockIdx.x & 15, bt = blockIdx.x >> 4;
    int tid = threadIdx.x;
    int lane = tid & 63, w = tid >> 6;
    int u = ut * 64 + lane;
    int bb[2] = { bt * 8 + w, bt * 8 + w + 4 };
    int tl = t & (TC2 - 1);

    float acc[2][4];
#pragma unroll
    for (int j = 0; j < 2; j++) {
        size_t g = ((size_t)bb[j] * TC2 + tl) * 4096;
        acc[j][0] = buf_s[g + u];
        acc[j][1] = buf_s[g + 1024 + u];
        acc[j][2] = buf_s[g + 2048 + u];
        acc[j][3] = buf_s[g + 3072 + u];
    }

    const float* hp = hroll + ((t - 1) & 1) * (NB * 1024);
    if (t > 0) {
        const float* h0 = hp + bb[0] * 1024;
        const float* h1 = hp + bb[1] * 1024;
#pragma unroll 4
        for (int k = 0; k < 1024; k++) {
            float hk0 = h0[k], hk1 = h1[k];
            const float* wr = Wh_s + ((size_t)k << 12);
            float wi = wr[u], wf = wr[u + 1024], wg = wr[u + 2048], wo = wr[u + 3072];
            acc[0][0] = fmaf(hk0, wi, acc[0][0]);
            acc[0][1] = fmaf(hk0, wf, acc[0][1]);
            acc[0][2] = fmaf(hk0, wg, acc[0][2]);
            acc[0][3] = fmaf(hk0, wo, acc[0][3]);
            acc[1][0] = fmaf(hk1, wi, acc[1][0]);
            acc[1][1] = fmaf(hk1, wf, acc[1][1]);
            acc[1][2] = fmaf(hk1, wg, acc[1][2]);
            acc[1][3] = fmaf(hk1, wo, acc[1][3]);
        }
    }

    float* hc = hroll + (t & 1) * (NB * 1024);
    float wu = attn_w[u];
    float hval[2];
#pragma unroll
    for (int j = 0; j < 2; j++) {
        int b = bb[j];
        float iv = sigf(acc[j][0]);
        float fv = sigf(acc[j][1]);
        float gv = tanhf(acc[j][2]);
        float ov = sigf(acc[j][3]);
        float cprev = (t > 0) ? c_s[b * 1024 + u] : 0.0f;
        float c = fv * cprev + iv * gv;
        float h = ov * tanhf(c);
        c_s[b * 1024 + u] = c;
        hc[b * 1024 + u] = h;
        hval[j] = h;
    }

    // fused attention score partial for step t (reduce over this u-tile)
#pragma unroll
    for (int j = 0; j < 2; j++) {
        float sc = tanhf(hval[j]) * wu;
#pragma unroll
        for (int off = 32; off > 0; off >>= 1) sc += __shfl_down(sc, off);
        if (lane == 0) atomicAdd(&scores[bb[j] * T_SEQ + t], sc);
    }

    // fused ctx accumulation for step t-1 (scores[t-1] complete by now)
    if (t > 0) {
#pragma unroll
        for (int j = 0; j < 2; j++) {
            int b = bb[j];
            float e = expf(scores[b * T_SEQ + (t - 1)]);
            ctx_num[b * 1024 + u] += e * hp[b * 1024 + u];
        }
    }
}

// ---------------- zero-init for scores+ctx_num (re-poisoned each launch) ---
__global__ __launch_bounds__(256) void zero_kernel(float* __restrict__ p, int n)
{
    int i = blockIdx.x * 256 + threadIdx.x;
    if (i < n) p[i] = 0.0f;
}

// ---------------- attention finalize ---------------------------------------
// 64 blocks (one per b), 256 threads. Softmax over scores -> out_alpha;
// ctx = (ctx_num + e^{s_511} h_511) / sum_t e^{s_t}.
__global__ __launch_bounds__(256) void attn_final(
    const float* __restrict__ scores, const float* __restrict__ ctx_num,
    const float* __restrict__ hroll, float* __restrict__ out_alpha,
    float* __restrict__ ctx)
{
    __shared__ float red[256];
    int b = blockIdx.x, tid = threadIdx.x;
    float v0 = scores[b * T_SEQ + tid];
    float v1 = scores[b * T_SEQ + tid + 256];
    red[tid] = fmaxf(v0, v1);
    __syncthreads();
    for (int s = 128; s > 0; s >>= 1) {
        if (tid < s) red[tid] = fmaxf(red[tid], red[tid + s]);
        __syncthreads();
    }
    float mx = red[0];
    __syncthreads();
    float e0 = expf(v0 - mx), e1 = expf(v1 - mx);
    red[tid] = e0 + e1;
    __syncthreads();
    for (int s = 128; s > 0; s >>= 1) {
        if (tid < s) red[tid] += red[tid + s];
        __syncthreads();
    }
    float d2 = red[0];
    float inv = 1.0f / d2;
    out_alpha[b * T_SEQ + tid] = e0 * inv;
    out_alpha[b * T_SEQ + tid + 256] = e1 * inv;

    // raw denominator (consistent with ctx_num's un-shifted exponentials)
    float d = d2 * expf(mx);
    float es511 = expf(scores[b * T_SEQ + 511]);
    const float* h511 = hroll + 1 * (NB * 1024) + b * 1024;  // 511&1 == 1
    float invd = 1.0f / d;
    float4 cn = *(const float4*)&ctx_num[b * 1024 + tid * 4];
    float4 hv = *(const float4*)&h511[tid * 4];
    float4 o;
    o.x = (cn.x + es511 * hv.x) * invd;
    o.y = (cn.y + es511 * hv.y) * invd;
    o.z = (cn.z + es511 * hv.z) * invd;
    o.w = (cn.w + es511 * hv.w) * invd;
    *(float4*)&ctx[b * 1024 + tid * 4] = o;
}

// ---------------- final linear: out[b,0:2] ---------------------------------
__global__ __launch_bounds__(64) void lin_kernel(
    const float* __restrict__ fcout, const float* __restrict__ lin_W,
    const float* __restrict__ lin_b, float* __restrict__ out)
{
    int b = blockIdx.x, lane = threadIdx.x;
    float p0 = 0.f, p1 = 0.f;
    for (int k = lane; k < 1024; k += 64) {
        float h = fcout[b * 1024 + k];
        p0 = fmaf(h, lin_W[k * 2 + 0], p0);
        p1 = fmaf(h, lin_W[k * 2 + 1], p1);
    }
#pragma unroll
    for (int off = 32; off > 0; off >>= 1) {
        p0 += __shfl_down(p0, off);
        p1 += __shfl_down(p1, off);
    }
    if (lane == 0) {
        out[b * 2 + 0] = p0 + lin_b[0];
        out[b * 2 + 1] = p1 + lin_b[1];
    }
}

__global__ void sentinel_kernel(float* out) { out[0] = 1.0e6f; }

extern "C" void kernel_launch(void* const* d_in, const int* in_sizes, int n_in,
                              void* d_out, int out_size, void* d_ws, size_t ws_size,
                              hipStream_t stream) {
    const float* x      = (const float*)d_in[0];
    const float* Wx_f   = (const float*)d_in[1];
    const float* Wh_f   = (const float*)d_in[2];
    const float* b_f    = (const float*)d_in[3];
    const float* Wx_b   = (const float*)d_in[4];
    const float* Wh_b   = (const float*)d_in[5];
    const float* b_b    = (const float*)d_in[6];
    const float* Wx_s   = (const float*)d_in[7];
    const float* Wh_s   = (const float*)d_in[8];
    const float* b_s    = (const float*)d_in[9];
    const float* attn_w = (const float*)d_in[10];
    const float* fc_W   = (const float*)d_in[11];
    const float* fc_b   = (const float*)d_in[12];
    const float* lin_W  = (const float*)d_in[13];
    const float* lin_b  = (const float*)d_in[14];
    float* out = (float*)d_out;

    float* w = (float*)d_ws;
    float* hb       = w; w += (size_t)NB * T_SEQ * 512;    // 64 MiB
    float* hf_chunk = w; w += (size_t)NB * TC1 * 512;      // 4 MiB
    // 16 MiB aliased chunk region: buf_b | buf_f | buf_s (disjoint lifetimes)
    float* buf_b = w;
    float* buf_f = w;
    float* buf_s = w;
    w += (size_t)NB * TC1 * 2048;                          // == NB*TC2*4096
    float* hf_roll = w; w += 2 * NB * 512;
    float* hroll   = w; w += 2 * NB * 1024;
    float* c_f     = w; w += NB * 512;
    float* c_b     = w; w += NB * 512;
    float* c_s     = w; w += NB * 1024;
    float* scores  = w; w += NB * T_SEQ;                   // adjacent with
    float* ctx_num = w; w += NB * 1024;                    // ctx_num: one zero
    float* ctx     = w; w += NB * 1024;
    float* fcout   = w; w += NB * 1024;

    size_t need_bytes = (size_t)((char*)w - (char*)d_ws);
    if (ws_size < need_bytes) {
        sentinel_kernel<<<1, 1, 0, stream>>>(out);
        return;
    }

    const int NCH1 = T_SEQ / TC1;  // 16

    // zero scores + ctx_num (contiguous span)
    {
        int n = NB * T_SEQ + NB * 1024;
        zero_kernel<<<(n + 255) / 256, 256, 0, stream>>>(scores, n);
    }

    // Phase 1: full backward scan (chunked x@Wx_b projections)
    for (int i = 0; i < NCH1; i++) {
        int t0b = T_SEQ - (i + 1) * TC1;
        sgemm_bias<<<dim3(2048 / 128, (NB * TC1) / 128), 256, 0, stream>>>(
            x, Wx_b, b_b, buf_b, NB * TC1, 2048, 300, 0, 0,
            1, t0b, 5, TC1 - 1, T_SEQ);
        for (int j = 0; j < TC1; j++)
            lstm1b_step<<<64, 256, 0, stream>>>(buf_b, Wh_b, hb, c_b,
                                                i * TC1 + j);
    }

    // Phase 2: forward scan interleaved with layer-2
    for (int i = 0; i < NCH1; i++) {
        int t0 = i * TC1;
        sgemm_bias<<<dim3(2048 / 128, (NB * TC1) / 128), 256, 0, stream>>>(
            x, Wx_f, b_f, buf_f, NB * TC1, 2048, 300, 0, 0,
            1, t0, 5, TC1 - 1, T_SEQ);
        for (int j = 0; j < TC1; j++)
            lstm1f_step<<<64, 256, 0, stream>>>(buf_f, Wh_f, hf_chunk,
                                                hf_roll, c_f, t0 + j);
        // layer-2 over two TC2 sub-chunks (buf_s aliases buf_f: buf_f dead)
        for (int h = 0; h < 2; h++) {
            int st0 = h * TC2;
            // buf_s = hf_chunk[.., st0..st0+16, :] @ Wx_s[0:512,:] + b_s
            sgemm_bias<<<dim3(4096 / 128, (NB * TC2) / 128), 256, 0, stream>>>(
                hf_chunk, Wx_s, b_s, buf_s, NB * TC2, 4096, 512, 0, 0,
                1, st0, 4, TC2 - 1, TC1);
            // buf_s += hb[.., t0+st0.., :] @ Wx_s[512:1024,:]
            sgemm_bias<<<dim3(4096 / 128, (NB * TC2) / 128), 256, 0, stream>>>(
                hb, Wx_s + (size_t)512 * 4096, b_s, buf_s,
                NB * TC2, 4096, 512, 0, 1,
                1, t0 + st0, 4, TC2 - 1, T_SEQ);
            for (int j = 0; j < TC2; j++)
                lstm2_step<<<128, 256, 0, stream>>>(
                    buf_s, Wh_s, hroll, c_s, scores, ctx_num, attn_w,
                    t0 + st0 + j);
        }
    }

    // Attention finalize: alpha output + ctx
    attn_final<<<NB, 256, 0, stream>>>(scores, ctx_num, hroll, out + 128, ctx);

    // fc (relu) + lin
    sgemm_bias<<<dim3(1024 / 128, 1), 256, 0, stream>>>(
        ctx, fc_W, fc_b, fcout, 64, 1024, 1024, 1, 0, 0, 0, 0, 0, 0);
    lin_kernel<<<NB, 64, 0, stream>>>(fcout, lin_W, lin_b, out);
}

// Round 6
// 48584.216 us; speedup vs baseline: 1.8737x; 1.8737x over previous
//
#include <hip/hip_runtime.h>
#include <cstddef>
#include <cstdint>

// SentimentAnalysis: BiLSTM(H=512) -> LSTM(1024) -> attn pool -> fc -> lin
// B=64, T=512, E=300, H=512, C=2. All fp32.
//
// Round-4 (passed, 91 ms) post-mortem: recurrent step kernels ran at
// 0.25-0.5 waves/SIMD with latency-bound serial K loops and 8x redundant
// weight reads. This round: K-split step kernels (wave kq owns a K-slice,
// LDS tree-reduce, wave 0 does the gate epilogue), 8 waves/CU, XCD-stable
// weight slices (<=2 MiB/XCD -> L2-resident across steps). GEMMs unchanged.

#define T_SEQ 512
#define NB 64
#define TC1 32   // layer-1 chunk (x-projections, lstm1 steps)
#define TC2 16   // layer-2 sub-chunk (buf_s, lstm2 steps)

__device__ __forceinline__ float sigf(float x) {
    return 1.0f / (1.0f + expf(-x));
}

// ---------------- Tiled SGEMM: C[M,N] = (A@B) [+ C] [+ bias], opt relu -----
// BM=BN=128, BK=8, 256 threads, 8x8 per thread.
// Row remap (chunked): local row r -> global A-row (r>>tsh)*Trows + t0 + (r&tcm).
__global__ __launch_bounds__(256) void sgemm_bias(
    const float* __restrict__ A, const float* __restrict__ B,
    const float* __restrict__ bias, float* __restrict__ C,
    int M, int N, int K, int act, int accum,
    int chunked, int t0, int tsh, int tcm, int Trows)
{
    __shared__ float As[8][128];
    __shared__ float Bs[8][128];
    int tid = threadIdx.x;
    int row0 = blockIdx.y * 128, col0 = blockIdx.x * 128;
    int arow = tid >> 1, ak0 = (tid & 1) * 4;
    int bk = tid >> 5, bcol = (tid & 31) * 4;
    int ty = tid >> 4, tx = tid & 15;
    float acc[8][8] = {};
    int r = row0 + arow;
    int grow = chunked ? ((r >> tsh) * Trows + t0 + (r & tcm)) : r;
    const float* Aptr = A + (size_t)grow * K;
    bool arow_ok = r < M;

    for (int k0 = 0; k0 < K; k0 += 8) {
#pragma unroll
        for (int i = 0; i < 4; i++) {
            int k = k0 + ak0 + i;
            As[ak0 + i][arow] = (arow_ok && k < K) ? Aptr[k] : 0.0f;
        }
        {
            int k = k0 + bk;
            float4 v = make_float4(0.f, 0.f, 0.f, 0.f);
            if (k < K) v = *(const float4*)&B[(size_t)k * N + col0 + bcol];
            *(float4*)&Bs[bk][bcol] = v;
        }
        __syncthreads();
#pragma unroll
        for (int kk = 0; kk < 8; kk++) {
            float a[8], b[8];
#pragma unroll
            for (int i = 0; i < 8; i++) a[i] = As[kk][ty * 8 + i];
#pragma unroll
            for (int j = 0; j < 8; j++) b[j] = Bs[kk][tx * 8 + j];
#pragma unroll
            for (int i = 0; i < 8; i++)
#pragma unroll
                for (int j = 0; j < 8; j++)
                    acc[i][j] = fmaf(a[i], b[j], acc[i][j]);
        }
        __syncthreads();
    }

    float bj[8];
#pragma unroll
    for (int j = 0; j < 8; j++) bj[j] = accum ? 0.0f : bias[col0 + tx * 8 + j];
#pragma unroll
    for (int i = 0; i < 8; i++) {
        int rr = row0 + ty * 8 + i;
        if (rr >= M) continue;
        float* crow = &C[(size_t)rr * N + col0 + tx * 8];
#pragma unroll
        for (int j = 0; j < 8; j += 4) {
            float4 v;
            v.x = acc[i][j + 0] + bj[j + 0];
            v.y = acc[i][j + 1] + bj[j + 1];
            v.z = acc[i][j + 2] + bj[j + 2];
            v.w = acc[i][j + 3] + bj[j + 3];
            if (accum) {
                float4 o = *(const float4*)&crow[j];
                v.x += o.x; v.y += o.y; v.z += o.z; v.w += o.w;
            }
            if (act) {
                v.x = fmaxf(v.x, 0.f); v.y = fmaxf(v.y, 0.f);
                v.z = fmaxf(v.z, 0.f); v.w = fmaxf(v.w, 0.f);
            }
            *(float4*)&crow[j] = v;
        }
    }
}

// ---------------- LSTM layer 1 step (one direction, K-split) ---------------
// grid 128 = ut(16) x bt(8); block 512 = kq(8) waves x 64 lanes.
// Lane: uq = lane&7 -> 4 units u0 = ut*32+uq*4; bq = lane>>3 -> b = bt*8+bq.
// Wave kq handles k in [kq*64, kq*64+64). LDS reduce, wave 0 does epilogue.
__global__ __launch_bounds__(512) void lstm1_step(
    const float* __restrict__ Gx, const float* __restrict__ Wh,
    float* __restrict__ hf_chunk, float* __restrict__ hf_roll,
    float* __restrict__ hb, float* __restrict__ cbuf_g,
    int t, int dir)
{
    __shared__ float red[7][16][64];
    int bx = blockIdx.x;
    int ut = bx & 15;
    int bt = bx >> 4;
    int tid = threadIdx.x;
    int kq = tid >> 6;
    int lane = tid & 63;
    int uq = lane & 7, bq = lane >> 3;
    int u0 = ut * 32 + uq * 4;
    int b = bt * 8 + bq;
    int t_eff = dir ? (T_SEQ - 1 - t) : t;
    int tl = dir ? (31 - (t & 31)) : (t & 31);

    float acc[16];
#pragma unroll
    for (int i = 0; i < 16; i++) acc[i] = 0.0f;

    if (t > 0) {
        const float* hp = dir
            ? hb + ((size_t)b * T_SEQ + t_eff + 1) * 512
            : hf_roll + ((t - 1) & 1) * (NB * 512) + b * 512;
        int k0 = kq * 64;
        for (int k = k0; k < k0 + 64; k += 4) {
            float4 h4 = *(const float4*)&hp[k];
            float hv[4] = { h4.x, h4.y, h4.z, h4.w };
#pragma unroll
            for (int kk = 0; kk < 4; kk++) {
                const float* wr = Wh + (size_t)(k + kk) * 2048;
#pragma unroll
                for (int g = 0; g < 4; g++) {
                    float4 w4 = *(const float4*)&wr[g * 512 + u0];
                    acc[g * 4 + 0] = fmaf(hv[kk], w4.x, acc[g * 4 + 0]);
                    acc[g * 4 + 1] = fmaf(hv[kk], w4.y, acc[g * 4 + 1]);
                    acc[g * 4 + 2] = fmaf(hv[kk], w4.z, acc[g * 4 + 2]);
                    acc[g * 4 + 3] = fmaf(hv[kk], w4.w, acc[g * 4 + 3]);
                }
            }
        }
    }

    if (kq > 0) {
#pragma unroll
        for (int i = 0; i < 16; i++) red[kq - 1][i][lane] = acc[i];
    }
    __syncthreads();
    if (kq != 0) return;
#pragma unroll
    for (int q = 0; q < 7; q++)
#pragma unroll
        for (int i = 0; i < 16; i++) acc[i] += red[q][i][lane];

    size_t gx = ((size_t)b * TC1 + tl) * 2048;
    float4 xi = *(const float4*)&Gx[gx + u0];
    float4 xf = *(const float4*)&Gx[gx + 512 + u0];
    float4 xg = *(const float4*)&Gx[gx + 1024 + u0];
    float4 xo = *(const float4*)&Gx[gx + 1536 + u0];
    float* cbuf = cbuf_g + b * 512 + u0;
    float4 cp = (t > 0) ? *(const float4*)cbuf
                        : make_float4(0.f, 0.f, 0.f, 0.f);
    float xiv[4] = { xi.x, xi.y, xi.z, xi.w };
    float xfv[4] = { xf.x, xf.y, xf.z, xf.w };
    float xgv[4] = { xg.x, xg.y, xg.z, xg.w };
    float xov[4] = { xo.x, xo.y, xo.z, xo.w };
    float cpv[4] = { cp.x, cp.y, cp.z, cp.w };
    float cn[4], hn[4];
#pragma unroll
    for (int i = 0; i < 4; i++) {
        float iv = sigf(acc[0 + i] + xiv[i]);
        float fv = sigf(acc[4 + i] + xfv[i]);
        float gv = tanhf(acc[8 + i] + xgv[i]);
        float ov = sigf(acc[12 + i] + xov[i]);
        float c = fv * cpv[i] + iv * gv;
        cn[i] = c;
        hn[i] = ov * tanhf(c);
    }
    *(float4*)cbuf = make_float4(cn[0], cn[1], cn[2], cn[3]);
    float4 h4 = make_float4(hn[0], hn[1], hn[2], hn[3]);
    if (dir) {
        *(float4*)&hb[((size_t)b * T_SEQ + t_eff) * 512 + u0] = h4;
    } else {
        *(float4*)&hf_roll[(t & 1) * (NB * 512) + b * 512 + u0] = h4;
        *(float4*)&hf_chunk[((size_t)b * TC1 + tl) * 512 + u0] = h4;
    }
}

// ---------------- LSTM layer 2 step (K-split) + fused score/ctx ------------
// grid 256 = ut(32) x bt(8); block 512 = kq(8) x 64 lanes.
// Lane: uq = lane&7 -> u0 = ut*32+uq*4; bq = lane>>3 -> b = bt*8+bq.
// Wave kq: k in [kq*128, kq*128+128). XCD slice: xcd = ut&7 stable.
__global__ __launch_bounds__(512) void lstm2_step(
    const float* __restrict__ buf_s, const float* __restrict__ Wh_s,
    float* __restrict__ hroll, float* __restrict__ c_s,
    float* __restrict__ scores, float* __restrict__ ctx_num,
    const float* __restrict__ attn_w, int t)
{
    __shared__ float red[7][16][64];
    int bx = blockIdx.x;
    int ut = bx & 31;
    int bt = bx >> 5;
    int tid = threadIdx.x;
    int kq = tid >> 6;
    int lane = tid & 63;
    int uq = lane & 7, bq = lane >> 3;
    int u0 = ut * 32 + uq * 4;
    int b = bt * 8 + bq;
    int tl = t & (TC2 - 1);

    const float* hp = hroll + ((t - 1) & 1) * (NB * 1024) + b * 1024;

    float acc[16];
#pragma unroll
    for (int i = 0; i < 16; i++) acc[i] = 0.0f;

    if (t > 0) {
        int k0 = kq * 128;
        for (int k = k0; k < k0 + 128; k += 4) {
            float4 h4 = *(const float4*)&hp[k];
            float hv[4] = { h4.x, h4.y, h4.z, h4.w };
#pragma unroll
            for (int kk = 0; kk < 4; kk++) {
                const float* wr = Wh_s + (size_t)(k + kk) * 4096;
#pragma unroll
                for (int g = 0; g < 4; g++) {
                    float4 w4 = *(const float4*)&wr[g * 1024 + u0];
                    acc[g * 4 + 0] = fmaf(hv[kk], w4.x, acc[g * 4 + 0]);
                    acc[g * 4 + 1] = fmaf(hv[kk], w4.y, acc[g * 4 + 1]);
                    acc[g * 4 + 2] = fmaf(hv[kk], w4.z, acc[g * 4 + 2]);
                    acc[g * 4 + 3] = fmaf(hv[kk], w4.w, acc[g * 4 + 3]);
                }
            }
        }
    }

    if (kq > 0) {
#pragma unroll
        for (int i = 0; i < 16; i++) red[kq - 1][i][lane] = acc[i];
    }
    __syncthreads();
    if (kq != 0) return;
#pragma unroll
    for (int q = 0; q < 7; q++)
#pragma unroll
        for (int i = 0; i < 16; i++) acc[i] += red[q][i][lane];

    size_t gx = ((size_t)b * TC2 + tl) * 4096;
    float4 xi = *(const float4*)&buf_s[gx + u0];
    float4 xf = *(const float4*)&buf_s[gx + 1024 + u0];
    float4 xg = *(const float4*)&buf_s[gx + 2048 + u0];
    float4 xo = *(const float4*)&buf_s[gx + 3072 + u0];
    float* cbuf = c_s + b * 1024 + u0;
    float4 cp = (t > 0) ? *(const float4*)cbuf
                        : make_float4(0.f, 0.f, 0.f, 0.f);
    float xiv[4] = { xi.x, xi.y, xi.z, xi.w };
    float xfv[4] = { xf.x, xf.y, xf.z, xf.w };
    float xgv[4] = { xg.x, xg.y, xg.z, xg.w };
    float xov[4] = { xo.x, xo.y, xo.z, xo.w };
    float cpv[4] = { cp.x, cp.y, cp.z, cp.w };
    float cn[4], hn[4];
#pragma unroll
    for (int i = 0; i < 4; i++) {
        float iv = sigf(acc[0 + i] + xiv[i]);
        float fv = sigf(acc[4 + i] + xfv[i]);
        float gv = tanhf(acc[8 + i] + xgv[i]);
        float ov = sigf(acc[12 + i] + xov[i]);
        float c = fv * cpv[i] + iv * gv;
        cn[i] = c;
        hn[i] = ov * tanhf(c);
    }
    *(float4*)cbuf = make_float4(cn[0], cn[1], cn[2], cn[3]);
    *(float4*)&hroll[(t & 1) * (NB * 1024) + b * 1024 + u0] =
        make_float4(hn[0], hn[1], hn[2], hn[3]);

    // fused attention score partial: this thread's 4 units, then the 8-lane
    // uq group (same b) via shfl -> 1 atomic per (block, b): 32 adds/address.
    float4 aw = *(const float4*)&attn_w[u0];
    float sc = tanhf(hn[0]) * aw.x + tanhf(hn[1]) * aw.y +
               tanhf(hn[2]) * aw.z + tanhf(hn[3]) * aw.w;
    sc += __shfl_down(sc, 4);
    sc += __shfl_down(sc, 2);
    sc += __shfl_down(sc, 1);
    if (uq == 0) atomicAdd(&scores[b * T_SEQ + t], sc);

    // fused ctx accumulation for step t-1 (scores[t-1] complete: prior launch)
    if (t > 0) {
        float e = expf(scores[b * T_SEQ + (t - 1)]);
        float4 hp4 = *(const float4*)&hp[u0];
        float4 cx = *(const float4*)&ctx_num[b * 1024 + u0];
        cx.x = fmaf(e, hp4.x, cx.x);
        cx.y = fmaf(e, hp4.y, cx.y);
        cx.z = fmaf(e, hp4.z, cx.z);
        cx.w = fmaf(e, hp4.w, cx.w);
        *(float4*)&ctx_num[b * 1024 + u0] = cx;
    }
}

// ---------------- zero-init for scores+ctx_num -----------------------------
__global__ __launch_bounds__(256) void zero_kernel(float* __restrict__ p, int n)
{
    int i = blockIdx.x * 256 + threadIdx.x;
    if (i < n) p[i] = 0.0f;
}

// ---------------- attention finalize ---------------------------------------
__global__ __launch_bounds__(256) void attn_final(
    const float* __restrict__ scores, const float* __restrict__ ctx_num,
    const float* __restrict__ hroll, float* __restrict__ out_alpha,
    float* __restrict__ ctx)
{
    __shared__ float red[256];
    int b = blockIdx.x, tid = threadIdx.x;
    float v0 = scores[b * T_SEQ + tid];
    float v1 = scores[b * T_SEQ + tid + 256];
    red[tid] = fmaxf(v0, v1);
    __syncthreads();
    for (int s = 128; s > 0; s >>= 1) {
        if (tid < s) red[tid] = fmaxf(red[tid], red[tid + s]);
        __syncthreads();
    }
    float mx = red[0];
    __syncthreads();
    float e0 = expf(v0 - mx), e1 = expf(v1 - mx);
    red[tid] = e0 + e1;
    __syncthreads();
    for (int s = 128; s > 0; s >>= 1) {
        if (tid < s) red[tid] += red[tid + s];
        __syncthreads();
    }
    float d2 = red[0];
    float inv = 1.0f / d2;
    out_alpha[b * T_SEQ + tid] = e0 * inv;
    out_alpha[b * T_SEQ + tid + 256] = e1 * inv;

    float d = d2 * expf(mx);
    float es511 = expf(scores[b * T_SEQ + 511]);
    const float* h511 = hroll + 1 * (NB * 1024) + b * 1024;  // 511&1 == 1
    float invd = 1.0f / d;
    float4 cn = *(const float4*)&ctx_num[b * 1024 + tid * 4];
    float4 hv = *(const float4*)&h511[tid * 4];
    float4 o;
    o.x = (cn.x + es511 * hv.x) * invd;
    o.y = (cn.y + es511 * hv.y) * invd;
    o.z = (cn.z + es511 * hv.z) * invd;
    o.w = (cn.w + es511 * hv.w) * invd;
    *(float4*)&ctx[b * 1024 + tid * 4] = o;
}

// ---------------- final linear: out[b,0:2] ---------------------------------
__global__ __launch_bounds__(64) void lin_kernel(
    const float* __restrict__ fcout, const float* __restrict__ lin_W,
    const float* __restrict__ lin_b, float* __restrict__ out)
{
    int b = blockIdx.x, lane = threadIdx.x;
    float p0 = 0.f, p1 = 0.f;
    for (int k = lane; k < 1024; k += 64) {
        float h = fcout[b * 1024 + k];
        p0 = fmaf(h, lin_W[k * 2 + 0], p0);
        p1 = fmaf(h, lin_W[k * 2 + 1], p1);
    }
#pragma unroll
    for (int off = 32; off > 0; off >>= 1) {
        p0 += __shfl_down(p0, off);
        p1 += __shfl_down(p1, off);
    }
    if (lane == 0) {
        out[b * 2 + 0] = p0 + lin_b[0];
        out[b * 2 + 1] = p1 + lin_b[1];
    }
}

__global__ void sentinel_kernel(float* out) { out[0] = 1.0e6f; }

extern "C" void kernel_launch(void* const* d_in, const int* in_sizes, int n_in,
                              void* d_out, int out_size, void* d_ws, size_t ws_size,
                              hipStream_t stream) {
    const float* x      = (const float*)d_in[0];
    const float* Wx_f   = (const float*)d_in[1];
    const float* Wh_f   = (const float*)d_in[2];
    const float* b_f    = (const float*)d_in[3];
    const float* Wx_b   = (const float*)d_in[4];
    const float* Wh_b   = (const float*)d_in[5];
    const float* b_b    = (const float*)d_in[6];
    const float* Wx_s   = (const float*)d_in[7];
    const float* Wh_s   = (const float*)d_in[8];
    const float* b_s    = (const float*)d_in[9];
    const float* attn_w = (const float*)d_in[10];
    const float* fc_W   = (const float*)d_in[11];
    const float* fc_b   = (const float*)d_in[12];
    const float* lin_W  = (const float*)d_in[13];
    const float* lin_b  = (const float*)d_in[14];
    float* out = (float*)d_out;

    float* w = (float*)d_ws;
    float* hb       = w; w += (size_t)NB * T_SEQ * 512;    // 64 MiB
    float* hf_chunk = w; w += (size_t)NB * TC1 * 512;      // 4 MiB
    float* buf_b = w;                                      // 16 MiB aliased
    float* buf_f = w;
    float* buf_s = w;
    w += (size_t)NB * TC1 * 2048;
    float* hf_roll = w; w += 2 * NB * 512;
    float* hroll   = w; w += 2 * NB * 1024;
    float* c_f     = w; w += NB * 512;
    float* c_b     = w; w += NB * 512;
    float* c_s     = w; w += NB * 1024;
    float* scores  = w; w += NB * T_SEQ;
    float* ctx_num = w; w += NB * 1024;
    float* ctx     = w; w += NB * 1024;
    float* fcout   = w; w += NB * 1024;

    size_t need_bytes = (size_t)((char*)w - (char*)d_ws);
    if (ws_size < need_bytes) {
        sentinel_kernel<<<1, 1, 0, stream>>>(out);
        return;
    }

    const int NCH1 = T_SEQ / TC1;  // 16

    {
        int n = NB * T_SEQ + NB * 1024;  // scores + ctx_num (contiguous)
        zero_kernel<<<(n + 255) / 256, 256, 0, stream>>>(scores, n);
    }

    // Phase 1: backward-only scan (chunked x@Wx_b projections + bwd steps)
    for (int i = 0; i < NCH1; i++) {
        int t0b = T_SEQ - (i + 1) * TC1;
        sgemm_bias<<<dim3(2048 / 128, (NB * TC1) / 128), 256, 0, stream>>>(
            x, Wx_b, b_b, buf_b, NB * TC1, 2048, 300, 0, 0,
            1, t0b, 5, TC1 - 1, T_SEQ);
        for (int j = 0; j < TC1; j++)
            lstm1_step<<<128, 512, 0, stream>>>(
                buf_b, Wh_b, hf_chunk, hf_roll, hb, c_b, i * TC1 + j, 1);
    }

    // Phase 2: forward scan interleaved with layer-2
    for (int i = 0; i < NCH1; i++) {
        int t0 = i * TC1;
        sgemm_bias<<<dim3(2048 / 128, (NB * TC1) / 128), 256, 0, stream>>>(
            x, Wx_f, b_f, buf_f, NB * TC1, 2048, 300, 0, 0,
            1, t0, 5, TC1 - 1, T_SEQ);
        for (int j = 0; j < TC1; j++)
            lstm1_step<<<128, 512, 0, stream>>>(
                buf_f, Wh_f, hf_chunk, hf_roll, hb, c_f, t0 + j, 0);
        for (int h = 0; h < 2; h++) {
            int st0 = h * TC2;
            sgemm_bias<<<dim3(4096 / 128, (NB * TC2) / 128), 256, 0, stream>>>(
                hf_chunk, Wx_s, b_s, buf_s, NB * TC2, 4096, 512, 0, 0,
                1, st0, 4, TC2 - 1, TC1);
            sgemm_bias<<<dim3(4096 / 128, (NB * TC2) / 128), 256, 0, stream>>>(
                hb, Wx_s + (size_t)512 * 4096, b_s, buf_s,
                NB * TC2, 4096, 512, 0, 1,
                1, t0 + st0, 4, TC2 - 1, T_SEQ);
            for (int j = 0; j < TC2; j++)
                lstm2_step<<<256, 512, 0, stream>>>(
                    buf_s, Wh_s, hroll, c_s, scores, ctx_num, attn_w,
                    t0 + st0 + j);
        }
    }

    attn_final<<<NB, 256, 0, stream>>>(scores, ctx_num, hroll, out + 128, ctx);
    sgemm_bias<<<dim3(1024 / 128, 1), 256, 0, stream>>>(
        ctx, fc_W, fc_b, fcout, 64, 1024, 1024, 1, 0, 0, 0, 0, 0, 0);
    lin_kernel<<<NB, 64, 0, stream>>>(fcout, lin_W, lin_b, out);
}